// Round 2
// baseline (523.209 us; speedup 1.0000x reference)
//
#include <hip/hip_runtime.h>
#include <math.h>

#define NB 512
#define NH 1024
#define NS 1024
#define ND 128
#define NK 32

typedef float fx4 __attribute__((ext_vector_type(4)));

// Light barrier: make LDS writes visible across waves WITHOUT draining the
// global-memory (vmcnt) pipeline. Copy loads/stores stay in flight across
// phase boundaries; only the final pre-fixup barrier does a full drain.
__device__ __forceinline__ void bar_lgkm() {
  asm volatile("s_waitcnt lgkmcnt(0)" ::: "memory");
  __builtin_amdgcn_s_barrier();
  __builtin_amdgcn_sched_barrier(0);
}
__device__ __forceinline__ void bar_full() {
  asm volatile("s_waitcnt vmcnt(0) lgkmcnt(0)" ::: "memory");
  __builtin_amdgcn_s_barrier();
  __builtin_amdgcn_sched_barrier(0);
}

// Fused kernel: per-batch compute with the streaming memory->out_mem copy
// woven through the compute phases. Copy sets are double-buffered: set i is
// loaded in interval i and stored in interval i+1, so the store's vmcnt wait
// has a whole compute interval of slack and barriers never drain the pipe.
__global__ __launch_bounds__(512, 4) void fused_kernel(
    const float* __restrict__ latent,      // [B,H]
    const float* __restrict__ memory,      // [B,S,D]
    const float* __restrict__ rq_w,        // [H,D]
    const float* __restrict__ rq_b,        // [D]
    const float* __restrict__ mem_key,     // [S,D]
    const float* __restrict__ wg_w,        // [H+D]
    const float* __restrict__ wg_b,        // [1]
    const float* __restrict__ dmd_w,       // [H+D]
    const float* __restrict__ dmd_b,       // [1]
    const float* __restrict__ ph_w,        // [H]
    const float* __restrict__ ph_b,        // [1]
    const float* __restrict__ wv_w,        // [H,D]
    const float* __restrict__ wv_b,        // [D]
    float* __restrict__ out_read,          // [B,D]
    float* __restrict__ out_mem,           // [B,S,D]
    float* __restrict__ out_wts)           // [B,S]
{
  const int b    = blockIdx.x;
  const int tid  = threadIdx.x;
  const int lane = tid & 63;
  const int wv   = tid >> 6;               // wave id, 0..7

  __shared__ float lat[NH];                // 4 KB
  __shared__ float wfull[NS];              // 4 KB
  __shared__ float part[512];              // 2 KB
  __shared__ __align__(16) float qv[ND];
  __shared__ float rd[ND];
  __shared__ float tvw[256];               // 8 waves x 32 candidates
  __shared__ int   tiw[256];
  __shared__ float wkL[NK];
  __shared__ int   tiL[NK];
  __shared__ __align__(16) float valw_s[ND];
  __shared__ float gred[24];
  __shared__ float scal[1];

  // block's 512 KB slice of memory: 32768 float4, 64 stripes of 512 f4
  const fx4* __restrict__ msrc = (const fx4*)memory + (size_t)b * (NS * ND / 4);
  fx4*       __restrict__ mdst = (fx4*)out_mem      + (size_t)b * (NS * ND / 4);
  fx4 bufA[8], bufB[8];
  int cur_l = 0, cur_s = 0;

#define CK_LOAD(BUF, N)  { _Pragma("unroll") \
    for (int j = 0; j < (N); ++j) \
      BUF[j] = __builtin_nontemporal_load(msrc + (size_t)(cur_l + j) * 512 + tid); \
    cur_l += (N); }
#define CK_STORE(BUF, N) { _Pragma("unroll") \
    for (int j = 0; j < (N); ++j) \
      __builtin_nontemporal_store(BUF[j], mdst + (size_t)(cur_s + j) * 512 + tid); \
    cur_s += (N); }

  // ---- interval 0 (A): latent row into LDS ----  load S0(A,8)
  CK_LOAD(bufA, 8);
  lat[tid]       = latent[(size_t)b * NH + tid];
  lat[tid + 512] = latent[(size_t)b * NH + tid + 512];
  bar_lgkm();

  // ---- interval 1 (B): query GEMV ----  load S1(B,4), store S0
  CK_LOAD(bufB, 4);
  CK_STORE(bufA, 8);
  {
    const int d = tid & 127, p = tid >> 7;
    const float* W = rq_w + (size_t)(p * 256) * ND + d;
    const float* L = lat + p * 256;
    float acc = 0.f;
    #pragma unroll 8
    for (int h = 0; h < 256; ++h) acc = fmaf(L[h], W[(size_t)h * ND], acc);
    part[tid] = acc;
  }
  bar_lgkm();

  // ---- interval 2 (qv reduce) ----  load S2(A,8), store S1
  CK_LOAD(bufA, 8);
  CK_STORE(bufB, 4);
  if (tid < ND)
    qv[tid] = part[tid] + part[tid + 128] + part[tid + 256] + part[tid + 384] + rq_b[tid];
  bar_lgkm();

  // ---- interval 3 (D: logits + E: per-wave top-32) ----  load S3(B,8), store S2
  CK_LOAD(bufB, 8);
  CK_STORE(bufA, 8);
  float r0 = 0.f, r1 = 0.f;
  {
    const float4* q4 = (const float4*)qv;
    const float4* k0 = (const float4*)(mem_key + (size_t)tid * ND);
    const float4* k1 = (const float4*)(mem_key + (size_t)(tid + 512) * ND);
    #pragma unroll 8
    for (int i = 0; i < ND / 4; ++i) {
      float4 q = q4[i];
      float4 x = k0[i];
      float4 y = k1[i];
      r0 += q.x * x.x + q.y * x.y + q.z * x.z + q.w * x.w;
      r1 += q.x * y.x + q.y * y.y + q.z * y.z + q.w * y.w;
    }
  }
  const float NEGINF = -3.0e38f;
  float selv = NEGINF; int seli = -1; float wkreg = 0.f;
  {
    const int s0 = tid, s1 = tid + 512;
    float v0 = r0, v1 = r1;
    for (int kk = 0; kk < NK; ++kk) {
      float best; int bi;
      if (v0 >= v1) { best = v0; bi = s0; } else { best = v1; bi = s1; }
      #pragma unroll
      for (int off = 1; off < 64; off <<= 1) {
        float ov = __shfl_xor(best, off);
        int   oi = __shfl_xor(bi, off);
        if (ov > best || (ov == best && oi < bi)) { best = ov; bi = oi; }
      }
      if (lane == 0) { tvw[(wv << 5) + kk] = best; tiw[(wv << 5) + kk] = bi; }
      if (bi == s0) v0 = NEGINF;
      if (bi == s1) v1 = NEGINF;
    }
  }
  wfull[tid] = 0.f; wfull[tid + 512] = 0.f;
  bar_lgkm();

  // ---- interval 4 (F: wave-0 merge; other waves just stream) ---- load S4(A,8), store S3
  CK_LOAD(bufA, 8);
  CK_STORE(bufB, 8);
  if (wv == 0) {
    float m0 = tvw[lane], m1 = tvw[lane + 64], m2 = tvw[lane + 128], m3 = tvw[lane + 192];
    int   i0 = tiw[lane], i1 = tiw[lane + 64], i2 = tiw[lane + 128], i3 = tiw[lane + 192];
    for (int kk = 0; kk < NK; ++kk) {
      float best = m0; int bi = i0;
      if (m1 > best || (m1 == best && i1 < bi)) { best = m1; bi = i1; }
      if (m2 > best || (m2 == best && i2 < bi)) { best = m2; bi = i2; }
      if (m3 > best || (m3 == best && i3 < bi)) { best = m3; bi = i3; }
      #pragma unroll
      for (int off = 1; off < 64; off <<= 1) {
        float ov = __shfl_xor(best, off);
        int   oi = __shfl_xor(bi, off);
        if (ov > best || (ov == best && oi < bi)) { best = ov; bi = oi; }
      }
      if (kk == lane) { selv = best; seli = bi; }
      if (bi == i0) m0 = NEGINF;
      if (bi == i1) m1 = NEGINF;
      if (bi == i2) m2 = NEGINF;
      if (bi == i3) m3 = NEGINF;
    }
    float maxv = __shfl(selv, 0);
    float e = (lane < NK) ? expf(selv - maxv) : 0.f;
    float s = e;
    #pragma unroll
    for (int off = 1; off < 64; off <<= 1) s += __shfl_xor(s, off);
    wkreg = e / s;
    if (lane < NK) { wkL[lane] = wkreg; tiL[lane] = seli; }
  }
  bar_lgkm();

  // ---- interval 5 (G: scatter weights; gather read) ----  load S5(B,4), store S4
  CK_LOAD(bufB, 4);
  CK_STORE(bufA, 8);
  if (wv == 0 && lane < NK) wfull[seli] = wkreg;
  {
    const int d = tid & 127, p = tid >> 7;
    const float* mb = memory + (size_t)b * NS * ND;
    float racc = 0.f;
    #pragma unroll
    for (int k = p * 8; k < p * 8 + 8; ++k)
      racc = fmaf(wkL[k], mb[(size_t)tiL[k] * ND + d], racc);
    part[tid] = racc;
  }
  bar_lgkm();

  // ---- interval 6 (rd reduce) ----  load S6(A,8), store S5
  CK_LOAD(bufA, 8);
  CK_STORE(bufB, 4);
  if (tid < ND) {
    float r = part[tid] + part[tid + 128] + part[tid + 256] + part[tid + 384];
    rd[tid] = r;
    out_read[(size_t)b * ND + tid] = r;
  }
  bar_lgkm();

  // ---- interval 7 (I1: gate dots + value GEMV) ----  load S7(B,4), store S6
  CK_LOAD(bufB, 4);
  CK_STORE(bufA, 8);
  {
    float l0 = lat[tid], l1 = lat[tid + 512];
    float p1 = l0 * wg_w[tid]  + l1 * wg_w[tid + 512];
    float p2 = l0 * dmd_w[tid] + l1 * dmd_w[tid + 512];
    float p3 = l0 * ph_w[tid]  + l1 * ph_w[tid + 512];
    if (tid < ND) {
      float r = rd[tid];
      p1 += r * wg_w[NH + tid];
      p2 += r * dmd_w[NH + tid];
    }
    #pragma unroll
    for (int off = 1; off < 64; off <<= 1) {
      p1 += __shfl_xor(p1, off);
      p2 += __shfl_xor(p2, off);
      p3 += __shfl_xor(p3, off);
    }
    if (lane == 0) { gred[wv] = p1; gred[8 + wv] = p2; gred[16 + wv] = p3; }
  }
  {
    const int d = tid & 127, p = tid >> 7;
    const float* W = wv_w + (size_t)(p * 256) * ND + d;
    const float* L = lat + p * 256;
    float acc = 0.f;
    #pragma unroll 8
    for (int h = 0; h < 256; ++h) acc = fmaf(L[h], W[(size_t)h * ND], acc);
    part[tid] = acc;
  }
  bar_lgkm();

  // ---- interval 8 (I2: gate scalar) ----  load S8(A,6), store S7
  CK_LOAD(bufA, 6);
  CK_STORE(bufB, 4);
  if (tid == 0) {
    float z1 = wg_b[0], z2 = dmd_b[0], z3 = ph_b[0];
    #pragma unroll
    for (int k = 0; k < 8; ++k) { z1 += gred[k]; z2 += gred[8 + k]; z3 += gred[16 + k]; }
    float g  = 1.f / (1.f + expf(-z1));
    float dm = tanhf(z2);
    g = g * (0.75f + 0.25f * (dm + 1.f));
    g = fminf(fmaxf(g, 0.f), 1.f);
    g = g * (0.5f * (1.f + cosf(z3)));
    scal[0] = g;
  }
  bar_lgkm();

  // ---- interval 9 (J: weights out + value vector) ----  load S9(B,6), store S8
  CK_LOAD(bufB, 6);
  CK_STORE(bufA, 6);
  {
    float w0 = wfull[tid], w1 = wfull[tid + 512];
    out_wts[(size_t)b * NS + tid]       = w0;
    out_wts[(size_t)b * NS + tid + 512] = w1;
    if (tid < ND)
      valw_s[tid] = part[tid] + part[tid + 128] + part[tid + 256] + part[tid + 384] + wv_b[tid];
  }
  bar_lgkm();

  // ---- interval 10: store S9, FULL drain (bulk stores must complete before
  // the fixup stores can touch the same rows), then sparse 32-row blend ----
  CK_STORE(bufB, 6);
  bar_full();
  {
    const float g = scal[0];
    const fx4* v4 = (const fx4*)valw_s;
    #pragma unroll
    for (int u = 0; u < 2; ++u) {
      const int idx = tid + u * 512;        // 0..1023 = 32 rows x 32 f4
      const int k   = idx >> 5;
      const int c   = idx & 31;
      const float w = g * wkL[k];
      const int row = tiL[k];
      const fx4 m = msrc[(size_t)row * 32 + c];
      __builtin_nontemporal_store((1.f - w) * m + w * v4[c],
                                  mdst + (size_t)row * 32 + c);
    }
  }
#undef CK_LOAD
#undef CK_STORE
}

extern "C" void kernel_launch(void* const* d_in, const int* in_sizes, int n_in,
                              void* d_out, int out_size, void* d_ws, size_t ws_size,
                              hipStream_t stream) {
  const float* latent  = (const float*)d_in[0];
  const float* memory  = (const float*)d_in[1];
  const float* rq_w    = (const float*)d_in[2];
  const float* rq_b    = (const float*)d_in[3];
  const float* mem_key = (const float*)d_in[4];
  const float* wg_w    = (const float*)d_in[5];
  const float* wg_b    = (const float*)d_in[6];
  const float* dmd_w   = (const float*)d_in[7];
  const float* dmd_b   = (const float*)d_in[8];
  const float* ph_w    = (const float*)d_in[9];
  const float* ph_b    = (const float*)d_in[10];
  const float* wv_w    = (const float*)d_in[11];
  const float* wv_b    = (const float*)d_in[12];

  float* out_read = (float*)d_out;                          // [B,D]
  float* out_mem  = out_read + (size_t)NB * ND;             // [B,S,D]
  float* out_wts  = out_mem + (size_t)NB * NS * ND;         // [B,S]

  fused_kernel<<<NB, 512, 0, stream>>>(
      latent, memory, rq_w, rq_b, mem_key, wg_w, wg_b, dmd_w, dmd_b,
      ph_w, ph_b, wv_w, wv_b, out_read, out_mem, out_wts);
}

// Round 3
// 507.138 us; speedup vs baseline: 1.0317x; 1.0317x over previous
//
#include <hip/hip_runtime.h>
#include <math.h>

#define NB 512
#define NH 1024
#define NS 1024
#define ND 128
#define NK 32

typedef float fx4 __attribute__((ext_vector_type(4)));

// Light barrier: LDS ordering only; global loads/stores stay in flight.
__device__ __forceinline__ void bar_lgkm() {
  asm volatile("s_waitcnt lgkmcnt(0)" ::: "memory");
  __builtin_amdgcn_s_barrier();
}
__device__ __forceinline__ void bar_full() {
  asm volatile("s_waitcnt vmcnt(0) lgkmcnt(0)" ::: "memory");
  __builtin_amdgcn_s_barrier();
}

// Fused: per-batch compute + streaming copy woven through phases.
// This rev: all hot GEMV/gather loads are float4 (dwordx4) — the prior rev
// issued 4096 global_load_dword wave-insts/block in the two H x D GEMVs,
// which we believe is the VMEM-issue bottleneck.
__global__ __launch_bounds__(512, 4) void fused_kernel(
    const float* __restrict__ latent,      // [B,H]
    const float* __restrict__ memory,      // [B,S,D]
    const float* __restrict__ rq_w,        // [H,D]
    const float* __restrict__ rq_b,        // [D]
    const float* __restrict__ mem_key,     // [S,D]
    const float* __restrict__ wg_w,        // [H+D]
    const float* __restrict__ wg_b,        // [1]
    const float* __restrict__ dmd_w,       // [H+D]
    const float* __restrict__ dmd_b,       // [1]
    const float* __restrict__ ph_w,        // [H]
    const float* __restrict__ ph_b,        // [1]
    const float* __restrict__ wv_w,        // [H,D]
    const float* __restrict__ wv_b,        // [D]
    float* __restrict__ out_read,          // [B,D]
    float* __restrict__ out_mem,           // [B,S,D]
    float* __restrict__ out_wts)           // [B,S]
{
  const int b    = blockIdx.x;
  const int tid  = threadIdx.x;
  const int lane = tid & 63;
  const int wv   = tid >> 6;               // wave id, 0..7

  __shared__ __align__(16) float lat[NH];      // 4 KB
  __shared__ __align__(16) float wfull[NS];    // 4 KB
  __shared__ __align__(16) fx4   part4[512];   // 8 KB  [16 p][32 og]
  __shared__ __align__(16) float qv[ND];
  __shared__ float rd[ND];
  __shared__ float tvw[256];               // 8 waves x 32 candidates
  __shared__ int   tiw[256];
  __shared__ float wkL[NK];
  __shared__ int   tiL[NK];
  __shared__ __align__(16) float valw_s[ND];
  __shared__ float gred[24];
  __shared__ float scal[1];

  float* part4f = (float*)part4;

  // block's 512 KB slice of memory: 32768 float4, 64 stripes of 512 f4
  const fx4* __restrict__ msrc = (const fx4*)memory + (size_t)b * (NS * ND / 4);
  fx4*       __restrict__ mdst = (fx4*)out_mem      + (size_t)b * (NS * ND / 4);
  fx4 bufA[8], bufB[8];
  int cur_l = 0, cur_s = 0;

#define CK_LOAD(BUF, N)  { _Pragma("unroll") \
    for (int j = 0; j < (N); ++j) \
      BUF[j] = __builtin_nontemporal_load(msrc + (size_t)(cur_l + j) * 512 + tid); \
    cur_l += (N); }
#define CK_STORE(BUF, N) { _Pragma("unroll") \
    for (int j = 0; j < (N); ++j) \
      __builtin_nontemporal_store(BUF[j], mdst + (size_t)(cur_s + j) * 512 + tid); \
    cur_s += (N); }

  const int og = tid & 31;                 // output group: 4 consecutive dims
  const int pp = tid >> 5;                 // partition 0..15 (64 h each)
  const fx4* lat4 = (const fx4*)lat;

  // ---- interval 0 (A): latent row into LDS (float4) ----  load S0(A,8)
  CK_LOAD(bufA, 8);
  if (tid < 256)
    ((fx4*)lat)[tid] = ((const fx4*)(latent + (size_t)b * NH))[tid];
  bar_lgkm();

  // ---- interval 1 (B): query GEMV, float4 weight rows ----  load S1(B,4), store S0
  CK_LOAD(bufB, 4);
  CK_STORE(bufA, 8);
  {
    const fx4* W4 = (const fx4*)rq_w;      // [1024][32] f4
    fx4 acc = {0.f, 0.f, 0.f, 0.f};
    const int hbase = pp * 64;
    #pragma unroll 4
    for (int j = 0; j < 16; ++j) {
      fx4 l4 = lat4[(hbase >> 2) + j];
      acc += l4.x * W4[(size_t)(hbase + 4*j    ) * 32 + og];
      acc += l4.y * W4[(size_t)(hbase + 4*j + 1) * 32 + og];
      acc += l4.z * W4[(size_t)(hbase + 4*j + 2) * 32 + og];
      acc += l4.w * W4[(size_t)(hbase + 4*j + 3) * 32 + og];
    }
    part4[pp * 32 + og] = acc;
  }
  bar_lgkm();

  // ---- interval 2 (qv reduce over 16 partitions) ----  load S2(A,8), store S1
  CK_LOAD(bufA, 8);
  CK_STORE(bufB, 4);
  if (tid < ND) {
    float q = rq_b[tid];
    #pragma unroll
    for (int p = 0; p < 16; ++p) q += part4f[p * 128 + tid];
    qv[tid] = q;
  }
  bar_lgkm();

  // ---- interval 3 (D: logits + E: per-wave top-32) ----  load S3(B,8), store S2
  CK_LOAD(bufB, 8);
  CK_STORE(bufA, 8);
  float r0 = 0.f, r1 = 0.f;
  {
    const float4* q4 = (const float4*)qv;
    const float4* k0 = (const float4*)(mem_key + (size_t)tid * ND);
    const float4* k1 = (const float4*)(mem_key + (size_t)(tid + 512) * ND);
    #pragma unroll 8
    for (int i = 0; i < ND / 4; ++i) {
      float4 q = q4[i];
      float4 x = k0[i];
      float4 y = k1[i];
      r0 += q.x * x.x + q.y * x.y + q.z * x.z + q.w * x.w;
      r1 += q.x * y.x + q.y * y.y + q.z * y.z + q.w * y.w;
    }
  }
  const float NEGINF = -3.0e38f;
  float selv = NEGINF; int seli = -1; float wkreg = 0.f;
  {
    const int s0 = tid, s1 = tid + 512;
    float v0 = r0, v1 = r1;
    for (int kk = 0; kk < NK; ++kk) {
      float best; int bi;
      if (v0 >= v1) { best = v0; bi = s0; } else { best = v1; bi = s1; }
      #pragma unroll
      for (int off = 1; off < 64; off <<= 1) {
        float ov = __shfl_xor(best, off);
        int   oi = __shfl_xor(bi, off);
        if (ov > best || (ov == best && oi < bi)) { best = ov; bi = oi; }
      }
      if (lane == 0) { tvw[(wv << 5) + kk] = best; tiw[(wv << 5) + kk] = bi; }
      if (bi == s0) v0 = NEGINF;
      if (bi == s1) v1 = NEGINF;
    }
  }
  wfull[tid] = 0.f; wfull[tid + 512] = 0.f;
  bar_lgkm();

  // ---- interval 4 (F: wave-0 merge) ---- load S4(A,8), store S3
  CK_LOAD(bufA, 8);
  CK_STORE(bufB, 8);
  if (wv == 0) {
    float m0 = tvw[lane], m1 = tvw[lane + 64], m2 = tvw[lane + 128], m3 = tvw[lane + 192];
    int   i0 = tiw[lane], i1 = tiw[lane + 64], i2 = tiw[lane + 128], i3 = tiw[lane + 192];
    for (int kk = 0; kk < NK; ++kk) {
      float best = m0; int bi = i0;
      if (m1 > best || (m1 == best && i1 < bi)) { best = m1; bi = i1; }
      if (m2 > best || (m2 == best && i2 < bi)) { best = m2; bi = i2; }
      if (m3 > best || (m3 == best && i3 < bi)) { best = m3; bi = i3; }
      #pragma unroll
      for (int off = 1; off < 64; off <<= 1) {
        float ov = __shfl_xor(best, off);
        int   oi = __shfl_xor(bi, off);
        if (ov > best || (ov == best && oi < bi)) { best = ov; bi = oi; }
      }
      if (kk == lane) { selv = best; seli = bi; }
      if (bi == i0) m0 = NEGINF;
      if (bi == i1) m1 = NEGINF;
      if (bi == i2) m2 = NEGINF;
      if (bi == i3) m3 = NEGINF;
    }
    float maxv = __shfl(selv, 0);
    float e = (lane < NK) ? expf(selv - maxv) : 0.f;
    float s = e;
    #pragma unroll
    for (int off = 1; off < 64; off <<= 1) s += __shfl_xor(s, off);
    wkreg = e / s;
    if (lane < NK) { wkL[lane] = wkreg; tiL[lane] = seli; }
  }
  bar_lgkm();

  // ---- interval 5 (G: scatter weights; float4 gather of 2 rows) ---- load S5(B,4), store S4
  CK_LOAD(bufB, 4);
  CK_STORE(bufA, 8);
  if (wv == 0 && lane < NK) wfull[seli] = wkreg;
  {
    const fx4* mb4 = (const fx4*)(memory + (size_t)b * NS * ND);
    const int k0i = pp, k1i = pp + 16;
    fx4 racc = wkL[k0i] * mb4[(size_t)tiL[k0i] * 32 + og]
             + wkL[k1i] * mb4[(size_t)tiL[k1i] * 32 + og];
    part4[pp * 32 + og] = racc;
  }
  bar_lgkm();

  // ---- interval 6 (rd reduce) ----  load S6(A,8), store S5
  CK_LOAD(bufA, 8);
  CK_STORE(bufB, 4);
  if (tid < ND) {
    float r = 0.f;
    #pragma unroll
    for (int p = 0; p < 16; ++p) r += part4f[p * 128 + tid];
    rd[tid] = r;
    out_read[(size_t)b * ND + tid] = r;
  }
  bar_lgkm();

  // ---- interval 7 (I1: gate dots (f4) + value GEMV (f4)) ----  load S7(B,4), store S6
  CK_LOAD(bufB, 4);
  CK_STORE(bufA, 8);
  {
    float p1 = 0.f, p2 = 0.f, p3 = 0.f;
    if (tid < 256) {
      fx4 l4 = lat4[tid];
      fx4 a = ((const fx4*)wg_w)[tid];
      fx4 d4 = ((const fx4*)dmd_w)[tid];
      fx4 c4 = ((const fx4*)ph_w)[tid];
      p1 = l4.x*a.x + l4.y*a.y + l4.z*a.z + l4.w*a.w;
      p2 = l4.x*d4.x + l4.y*d4.y + l4.z*d4.z + l4.w*d4.w;
      p3 = l4.x*c4.x + l4.y*c4.y + l4.z*c4.z + l4.w*c4.w;
    } else if (tid < 384) {
      const int d = tid - 256;
      float r = rd[d];
      p1 = r * wg_w[NH + d];
      p2 = r * dmd_w[NH + d];
    }
    #pragma unroll
    for (int off = 1; off < 64; off <<= 1) {
      p1 += __shfl_xor(p1, off);
      p2 += __shfl_xor(p2, off);
      p3 += __shfl_xor(p3, off);
    }
    if (lane == 0) { gred[wv] = p1; gred[8 + wv] = p2; gred[16 + wv] = p3; }
  }
  {
    const fx4* W4 = (const fx4*)wv_w;      // [1024][32] f4
    fx4 acc = {0.f, 0.f, 0.f, 0.f};
    const int hbase = pp * 64;
    #pragma unroll 4
    for (int j = 0; j < 16; ++j) {
      fx4 l4 = lat4[(hbase >> 2) + j];
      acc += l4.x * W4[(size_t)(hbase + 4*j    ) * 32 + og];
      acc += l4.y * W4[(size_t)(hbase + 4*j + 1) * 32 + og];
      acc += l4.z * W4[(size_t)(hbase + 4*j + 2) * 32 + og];
      acc += l4.w * W4[(size_t)(hbase + 4*j + 3) * 32 + og];
    }
    part4[pp * 32 + og] = acc;
  }
  bar_lgkm();

  // ---- interval 8 (I2: gate scalar) ----  load S8(A,6), store S7
  CK_LOAD(bufA, 6);
  CK_STORE(bufB, 4);
  if (tid == 0) {
    float z1 = wg_b[0], z2 = dmd_b[0], z3 = ph_b[0];
    #pragma unroll
    for (int k = 0; k < 8; ++k) { z1 += gred[k]; z2 += gred[8 + k]; z3 += gred[16 + k]; }
    float g  = 1.f / (1.f + expf(-z1));
    float dm = tanhf(z2);
    g = g * (0.75f + 0.25f * (dm + 1.f));
    g = fminf(fmaxf(g, 0.f), 1.f);
    g = g * (0.5f * (1.f + cosf(z3)));
    scal[0] = g;
  }
  bar_lgkm();

  // ---- interval 9 (J: weights out (f4) + value reduce) ----  load S9(B,6), store S8
  CK_LOAD(bufB, 6);
  CK_STORE(bufA, 6);
  if (tid < 256)
    ((fx4*)(out_wts + (size_t)b * NS))[tid] = ((const fx4*)wfull)[tid];
  if (tid < ND) {
    float v = wv_b[tid];
    #pragma unroll
    for (int p = 0; p < 16; ++p) v += part4f[p * 128 + tid];
    valw_s[tid] = v;
  }
  bar_lgkm();

  // ---- interval 10: store S9, FULL drain, sparse 32-row blend fixup ----
  CK_STORE(bufB, 6);
  bar_full();
  {
    const float g = scal[0];
    const fx4* v4 = (const fx4*)valw_s;
    #pragma unroll
    for (int u = 0; u < 2; ++u) {
      const int idx = tid + u * 512;        // 0..1023 = 32 rows x 32 f4
      const int k   = idx >> 5;
      const int c   = idx & 31;
      const float w = g * wkL[k];
      const int row = tiL[k];
      const fx4 m = msrc[(size_t)row * 32 + c];
      __builtin_nontemporal_store((1.f - w) * m + w * v4[c],
                                  mdst + (size_t)row * 32 + c);
    }
  }
#undef CK_LOAD
#undef CK_STORE
}

extern "C" void kernel_launch(void* const* d_in, const int* in_sizes, int n_in,
                              void* d_out, int out_size, void* d_ws, size_t ws_size,
                              hipStream_t stream) {
  const float* latent  = (const float*)d_in[0];
  const float* memory  = (const float*)d_in[1];
  const float* rq_w    = (const float*)d_in[2];
  const float* rq_b    = (const float*)d_in[3];
  const float* mem_key = (const float*)d_in[4];
  const float* wg_w    = (const float*)d_in[5];
  const float* wg_b    = (const float*)d_in[6];
  const float* dmd_w   = (const float*)d_in[7];
  const float* dmd_b   = (const float*)d_in[8];
  const float* ph_w    = (const float*)d_in[9];
  const float* ph_b    = (const float*)d_in[10];
  const float* wv_w    = (const float*)d_in[11];
  const float* wv_b    = (const float*)d_in[12];

  float* out_read = (float*)d_out;                          // [B,D]
  float* out_mem  = out_read + (size_t)NB * ND;             // [B,S,D]
  float* out_wts  = out_mem + (size_t)NB * NS * ND;         // [B,S]

  fused_kernel<<<NB, 512, 0, stream>>>(
      latent, memory, rq_w, rq_b, mem_key, wg_w, wg_b, dmd_w, dmd_b,
      ph_w, ph_b, wv_w, wv_b, out_read, out_mem, out_wts);
}